// Round 12
// baseline (241.432 us; speedup 1.0000x reference)
//
#include <hip/hip_runtime.h>
#include <hip/hip_bf16.h>

// ---------------------------------------------------------------------------
// GCN 2-layer forward. Bucketed CSR (256-node buckets) + MFMA GEMM1
// (dbuf-A single-barrier, B direct-from-L2) + fused agg1+relu+GEMM2
// (16 nodes/blk) + fused agg2+log_softmax. Gathers: predicated-clamped,
// 16 rows in flight / wave (round-9 form; pairing regressed - L3-BW-bound).
// ---------------------------------------------------------------------------

typedef float f32x4 __attribute__((ext_vector_type(4)));
typedef short bf16x8 __attribute__((ext_vector_type(8)));

__device__ inline float bf16_lo(unsigned int p) {
    return __uint_as_float((p & 0xffffu) << 16);
}
__device__ inline float bf16_hi(unsigned int p) {
    return __uint_as_float(p & 0xffff0000u);
}
__device__ inline unsigned short bf16_bits(float f) {
    __hip_bfloat16 b = __float2bfloat16(f);
    return *reinterpret_cast<unsigned short*>(&b);
}
__device__ inline unsigned int pack_bf16(float a, float b) {
    return (unsigned int)bf16_bits(a) | ((unsigned int)bf16_bits(b) << 16);
}

#define EB 4096            // edges per block in bucketing passes
#define BSHIFT 8           // bucket = dst >> 8  (256 nodes/bucket, 391 buckets)

// ------- pass 1: per-(block,bucket) histogram + weight convert (merged) ----
__global__ __launch_bounds__(256) void hist_conv(const int* __restrict__ dst,
                                                 int* __restrict__ counts,   // [NBUCKET][NB_E]
                                                 const float* __restrict__ W1,
                                                 const float* __restrict__ W2,
                                                 __hip_bfloat16* __restrict__ W1t,
                                                 __hip_bfloat16* __restrict__ W2t,
                                                 int NB_E, int NBUCKET, int E) {
    const int b = blockIdx.x;
    const int tid = threadIdx.x;
    if (b < NB_E) {
        __shared__ int hist[512];
        for (int i = tid; i < NBUCKET; i += 256) hist[i] = 0;
        __syncthreads();
        const int e0 = b * EB;
        const int e1 = min(e0 + EB, E);
        for (int e = e0 + tid; e < e1; e += 256)
            atomicAdd(&hist[dst[e] >> BSHIFT], 1);
        __syncthreads();
        for (int i = tid; i < NBUCKET; i += 256)
            counts[(size_t)i * NB_E + b] = hist[i];
    } else if (b < NB_E + 256) {
        const int idx = (b - NB_E) * 256 + tid;        // 0 .. 128*512-1
        const int c = idx >> 9, k = idx & 511;
        W1t[idx] = __float2bfloat16(W1[k * 128 + c]);
    } else {
        const int idx = (b - NB_E - 256) * 256 + tid;  // 0 .. 64*128-1
        const int c = idx >> 7, k = idx & 127;
        W2t[idx] = __float2bfloat16(W2[k * 64 + c]);
    }
}

// ---------------- scan machinery (2-level, exclusive) ----------------
__global__ __launch_bounds__(256) void scan_block_sums(const int* __restrict__ v, int* __restrict__ bsum, int T) {
    __shared__ int s[256];
    int i = blockIdx.x * 256 + threadIdx.x;
    s[threadIdx.x] = (i < T) ? v[i] : 0;
    __syncthreads();
    for (int off = 128; off > 0; off >>= 1) {
        if (threadIdx.x < off) s[threadIdx.x] += s[threadIdx.x + off];
        __syncthreads();
    }
    if (threadIdx.x == 0) bsum[blockIdx.x] = s[0];
}

// fused: block base = sum of raw bsum[0..bid-1], then local exclusive scan
__global__ __launch_bounds__(256) void scan_offs(const int* __restrict__ v, const int* __restrict__ bsum,
                                                 int* __restrict__ offs, int T) {
    __shared__ int s[256];
    __shared__ int base_s;
    const int tid = threadIdx.x;
    int p = 0;
    for (int i = tid; i < (int)blockIdx.x; i += 256) p += bsum[i];
    s[tid] = p;
    __syncthreads();
    for (int off = 128; off > 0; off >>= 1) {
        if (tid < off) s[tid] += s[tid + off];
        __syncthreads();
    }
    if (tid == 0) base_s = s[0];
    __syncthreads();
    const int base = base_s;
    __syncthreads();
    int i = blockIdx.x * 256 + tid;
    int x = (i < T) ? v[i] : 0;
    s[tid] = x;
    __syncthreads();
    for (int off = 1; off < 256; off <<= 1) {
        int t = (tid >= off) ? s[tid - off] : 0;
        __syncthreads();
        s[tid] += t;
        __syncthreads();
    }
    if (i < T) offs[i] = s[tid] - x + base;
}

// ------ pass 3: bucket-major edge materialization (packed 4B records) ------
// record = src (bits 0..23) | local_dst (bits 24..31)
__global__ __launch_bounds__(256) void scatter_bucketed(const int* __restrict__ src,
                                                        const int* __restrict__ dst,
                                                        const int* __restrict__ offs,  // [NBUCKET][NB_E]
                                                        unsigned* __restrict__ ebuf,
                                                        int NB_E, int NBUCKET, int E) {
    __shared__ int lcur[512];
    const int tid = threadIdx.x;
    for (int i = tid; i < NBUCKET; i += 256)
        lcur[i] = offs[(size_t)i * NB_E + blockIdx.x];
    __syncthreads();
    const int e0 = blockIdx.x * EB;
    const int e1 = min(e0 + EB, E);
    for (int e = e0 + tid; e < e1; e += 256) {
        const int d = dst[e];
        const int s = src[e];
        const int pos = atomicAdd(&lcur[d >> BSHIFT], 1);
        ebuf[pos] = (unsigned)s | ((unsigned)(d & 255) << 24);
    }
}

// ---------------- pass 4: per-bucket CSR finalize (all LDS) ----------------
__global__ __launch_bounds__(256) void bucket_csr(const unsigned* __restrict__ ebuf,
                                                  const int* __restrict__ offs,
                                                  int* __restrict__ row_start,
                                                  int* __restrict__ cnt,
                                                  float* __restrict__ dinv,
                                                  int* __restrict__ srcs,
                                                  int NB_E, int NBUCKET, int N, int E) {
    __shared__ int lcnt[256];
    __shared__ int lscan[256];
    __shared__ int lcur[256];
    const int tid = threadIdx.x;
    const int b = blockIdx.x;
    const int node_base = b << BSHIFT;
    const int ebeg = offs[(size_t)b * NB_E];
    const int eend = (b + 1 < NBUCKET) ? offs[(size_t)(b + 1) * NB_E] : E;

    lcnt[tid] = 0;
    __syncthreads();
    for (int e = ebeg + tid; e < eend; e += 256)
        atomicAdd(&lcnt[ebuf[e] >> 24], 1);
    __syncthreads();

    int v = lcnt[tid];
    lscan[tid] = v;
    __syncthreads();
    for (int off = 1; off < 256; off <<= 1) {
        int t = (tid >= off) ? lscan[tid - off] : 0;
        __syncthreads();
        lscan[tid] += t;
        __syncthreads();
    }
    const int excl = lscan[tid] - v;

    const int node = node_base + tid;
    if (node < N) {
        row_start[node] = ebeg + excl;
        cnt[node]       = v;
        dinv[node]      = rsqrtf((float)(v + 1));
    }
    lcur[tid] = excl;
    __syncthreads();

    for (int e = ebeg + tid; e < eend; e += 256) {
        const unsigned p = ebuf[e];
        const int pos = ebeg + atomicAdd(&lcur[p >> 24], 1);
        srcs[pos] = (int)(p & 0xFFFFFFu);
    }
}

// ---- GEMM1: h' = dinv * (x @ W1)  (MFMA bf16) ----------------------------
// A double-buffered in LDS (single barrier / K-step); B fragments loaded
// directly from global (W1t is 128 KB, L2-resident, no LDS staging).
__global__ __launch_bounds__(256) void gemm1_mfma(const float* __restrict__ A,          // [M][512]
                                                  const __hip_bfloat16* __restrict__ Bt, // [128][512]
                                                  const float* __restrict__ dinv,
                                                  __hip_bfloat16* __restrict__ C,        // [M][128]
                                                  int M) {
    __shared__ __hip_bfloat16 As[2][128 * 64];   // 2 x 16 KB
    __shared__ float sdinv[128];
    const int tid  = threadIdx.x;
    const int lane = tid & 63;
    const int wid  = tid >> 6;
    const int wr   = wid >> 1, wc = wid & 1;
    const int g    = lane >> 4, l15 = lane & 15;
    const int row0 = blockIdx.x * 128;

    if (tid < 128) {
        int gr = row0 + tid;
        sdinv[tid] = dinv[gr < M ? gr : M - 1];
    }

    const int ar = tid >> 4;          // staging row within 16-row group
    const int ak = (tid & 15) * 4;    // staging k offset

    auto STAGE = [&](int kt, int buf) {
        #pragma unroll
        for (int it = 0; it < 8; ++it) {
            const int r = it * 16 + ar;
            int gr = row0 + r; if (gr >= M) gr = M - 1;
            const f32x4 v = *reinterpret_cast<const f32x4*>(A + (size_t)gr * 512 + kt * 64 + ak);
            ushort4 p;
            p.x = bf16_bits(v.x); p.y = bf16_bits(v.y);
            p.z = bf16_bits(v.z); p.w = bf16_bits(v.w);
            *reinterpret_cast<ushort4*>(&As[buf][r * 64 + (ak ^ ((r & 7) << 3))]) = p;
        }
    };

    f32x4 acc[4][4] = {};

    STAGE(0, 0);
    __syncthreads();
    for (int kt = 0; kt < 8; ++kt) {
        if (kt < 7) STAGE(kt + 1, (kt + 1) & 1);   // fill other buffer
        const int cur = kt & 1;
        #pragma unroll
        for (int kk = 0; kk < 2; ++kk) {
            bf16x8 af[4], bfr[4];
            const int k0 = kk * 32 + g * 8;
            #pragma unroll
            for (int i = 0; i < 4; ++i) {
                const int r = wr * 64 + i * 16 + l15;
                af[i] = *reinterpret_cast<const bf16x8*>(&As[cur][r * 64 + (k0 ^ ((r & 7) << 3))]);
            }
            #pragma unroll
            for (int j = 0; j < 4; ++j) {
                const int c = wc * 64 + j * 16 + l15;
                bfr[j] = *reinterpret_cast<const bf16x8*>(Bt + (size_t)c * 512 + kt * 64 + k0);
            }
            #pragma unroll
            for (int i = 0; i < 4; ++i)
                #pragma unroll
                for (int j = 0; j < 4; ++j)
                    acc[i][j] = __builtin_amdgcn_mfma_f32_16x16x32_bf16(af[i], bfr[j], acc[i][j], 0, 0, 0);
        }
        __syncthreads();   // staged buffer ready for next iter; reads of cur done
    }
    #pragma unroll
    for (int i = 0; i < 4; ++i) {
        #pragma unroll
        for (int q = 0; q < 4; ++q) {
            const int lr  = wr * 64 + i * 16 + g * 4 + q;
            const int row = row0 + lr;
            if (row < M) {
                const float dv = sdinv[lr];
                #pragma unroll
                for (int j = 0; j < 4; ++j)
                    C[(size_t)row * 128 + wc * 64 + j * 16 + l15] = __float2bfloat16(acc[i][j][q] * dv);
            }
        }
    }
}

// ---- fused agg1 + bias + relu + (r @ W2) + dinv scale -> h2' (bf16) ------
// Block: 256 thr = 4 waves = 16 nodes (each wave handles 4 nodes serially).
// Gather: predicated-clamped, 16 rows in flight per wave per iteration.
__global__ __launch_bounds__(256) void agg1_fused(const int* __restrict__ row_start,
                                                  const int* __restrict__ cnt,
                                                  const int* __restrict__ srcs,
                                                  const float* __restrict__ dinv,
                                                  const uint4* __restrict__ h4,   // [N][16] (128 bf16)
                                                  const float* __restrict__ b1,
                                                  const __hip_bfloat16* __restrict__ W2t, // [64][128]
                                                  __hip_bfloat16* __restrict__ h2,        // [N][64]
                                                  int N) {
    __shared__ __hip_bfloat16 w2s[64 * 128];   // 16 KB, swizzled
    __shared__ __hip_bfloat16 rs[16 * 128];    // 4 KB, all 16 rows valid
    const int tid  = threadIdx.x;
    const int w    = tid >> 6;
    const int lane = tid & 63;
    const int s    = lane >> 4, li = lane & 15;

    // stage W2t into LDS with swizzle: (c,k) -> c*128 + (k^((c&15)<<3))
    {
        const uint4* s4 = reinterpret_cast<const uint4*>(W2t);
        for (int i = tid; i < 1024; i += 256) {
            const int c = i >> 4;
            const int k = (i & 15) * 8;
            const uint4 v = s4[i];
            *reinterpret_cast<uint4*>(&w2s[c * 128 + (k ^ ((c & 15) << 3))]) = v;
        }
    }

    const int base = blockIdx.x * 16;

    #pragma unroll 1
    for (int q = 0; q < 4; ++q) {
        const int node = base + w * 4 + q;
        const bool active = node < N;

        float acc[8] = {};

        int beg = 0, num = 0;
        if (active) { beg = row_start[node]; num = cnt[node]; }
        if (active && s == 0) {   // self-loop once
            const uint4 v = h4[(size_t)node * 16 + li];
            acc[0] += bf16_lo(v.x); acc[1] += bf16_hi(v.x);
            acc[2] += bf16_lo(v.y); acc[3] += bf16_hi(v.y);
            acc[4] += bf16_lo(v.z); acc[5] += bf16_hi(v.z);
            acc[6] += bf16_lo(v.w); acc[7] += bf16_hi(v.w);
        }

        // predicated gather: 16 edges / iteration, no divergent tail
        for (int j = 0; j < num; j += 16) {
            uint4 vv[4];
            float mm[4];
            #pragma unroll
            for (int u = 0; u < 4; ++u) {
                const int jj = j + u * 4 + s;
                mm[u] = (jj < num) ? 1.0f : 0.0f;
                const int idx = (jj < num) ? jj : (num - 1);
                vv[u] = h4[(size_t)srcs[beg + idx] * 16 + li];
            }
            #pragma unroll
            for (int u = 0; u < 4; ++u) {
                const float m = mm[u];
                acc[0] = fmaf(bf16_lo(vv[u].x), m, acc[0]);
                acc[1] = fmaf(bf16_hi(vv[u].x), m, acc[1]);
                acc[2] = fmaf(bf16_lo(vv[u].y), m, acc[2]);
                acc[3] = fmaf(bf16_hi(vv[u].y), m, acc[3]);
                acc[4] = fmaf(bf16_lo(vv[u].z), m, acc[4]);
                acc[5] = fmaf(bf16_hi(vv[u].z), m, acc[5]);
                acc[6] = fmaf(bf16_lo(vv[u].w), m, acc[6]);
                acc[7] = fmaf(bf16_hi(vv[u].w), m, acc[7]);
            }
        }
        #pragma unroll
        for (int t = 0; t < 8; ++t) {
            acc[t] += __shfl_xor(acc[t], 16);
            acc[t] += __shfl_xor(acc[t], 32);
        }
        if (active && s == 0) {
            const float di = dinv[node];
            const float4 bb0 = reinterpret_cast<const float4*>(b1)[li * 2];
            const float4 bb1 = reinterpret_cast<const float4*>(b1)[li * 2 + 1];
            const float r0 = fmaxf(fmaf(di, acc[0], bb0.x), 0.0f);
            const float r1 = fmaxf(fmaf(di, acc[1], bb0.y), 0.0f);
            const float r2 = fmaxf(fmaf(di, acc[2], bb0.z), 0.0f);
            const float r3 = fmaxf(fmaf(di, acc[3], bb0.w), 0.0f);
            const float r4 = fmaxf(fmaf(di, acc[4], bb1.x), 0.0f);
            const float r5 = fmaxf(fmaf(di, acc[5], bb1.y), 0.0f);
            const float r6 = fmaxf(fmaf(di, acc[6], bb1.z), 0.0f);
            const float r7 = fmaxf(fmaf(di, acc[7], bb1.w), 0.0f);
            uint4 o;
            o.x = pack_bf16(r0, r1); o.y = pack_bf16(r2, r3);
            o.z = pack_bf16(r4, r5); o.w = pack_bf16(r6, r7);
            const int row = w * 4 + q;
            const int k = li * 8;
            *reinterpret_cast<uint4*>(&rs[row * 128 + (k ^ ((row & 15) << 3))]) = o;
        }
    }
    __syncthreads();   // uniform: no early returns above

    // full mini-GEMM: C[0..15][w*16 .. w*16+15], K=128  (lane reads A row li)
    f32x4 oacc = {};
    #pragma unroll
    for (int kk = 0; kk < 4; ++kk) {
        const int k0 = kk * 32 + s * 8;
        const bf16x8 af = *reinterpret_cast<const bf16x8*>(&rs[li * 128 + (k0 ^ ((li & 15) << 3))]);
        const int c = w * 16 + li;
        const bf16x8 bfr = *reinterpret_cast<const bf16x8*>(&w2s[c * 128 + (k0 ^ ((c & 15) << 3))]);
        oacc = __builtin_amdgcn_mfma_f32_16x16x32_bf16(af, bfr, oacc, 0, 0, 0);
    }
    // D layout: row = s*4 + reg, col = li within wave's 16-col block
    #pragma unroll
    for (int q = 0; q < 4; ++q) {
        const int nd = base + s * 4 + q;
        if (nd < N) {
            const float dv = dinv[nd];
            h2[(size_t)nd * 64 + w * 16 + li] = __float2bfloat16(oacc[q] * dv);
        }
    }
}

// --- layer-2 agg + bias + log_softmax: 8 slots x 8 lanes x uint4 (full row) -
__global__ __launch_bounds__(256) void agg2_lsm8(const int* __restrict__ row_start,
                                                 const int* __restrict__ cnt,
                                                 const int* __restrict__ srcs,
                                                 const float* __restrict__ dinv,
                                                 const uint4* __restrict__ h2r,  // [N][8] (64 bf16)
                                                 const float* __restrict__ b2,
                                                 float* __restrict__ out, int N) {
    int node = blockIdx.x * 4 + (threadIdx.x >> 6);
    if (node >= N) return;
    const int lane = threadIdx.x & 63;
    const int s = lane >> 3, li = lane & 7;

    float acc[8] = {};
    if (s == 0) {   // self-loop
        const uint4 v = h2r[(size_t)node * 8 + li];
        acc[0] += bf16_lo(v.x); acc[1] += bf16_hi(v.x);
        acc[2] += bf16_lo(v.y); acc[3] += bf16_hi(v.y);
        acc[4] += bf16_lo(v.z); acc[5] += bf16_hi(v.z);
        acc[6] += bf16_lo(v.w); acc[7] += bf16_hi(v.w);
    }
    const int beg = row_start[node];
    const int num = cnt[node];
    for (int j = 0; j < num; j += 16) {
        uint4 vv[2];
        float mm[2];
        #pragma unroll
        for (int u = 0; u < 2; ++u) {
            const int jj = j + u * 8 + s;
            mm[u] = (jj < num) ? 1.0f : 0.0f;
            const int idx = (jj < num) ? jj : (num - 1);
            vv[u] = h2r[(size_t)srcs[beg + idx] * 8 + li];
        }
        #pragma unroll
        for (int u = 0; u < 2; ++u) {
            const float m = mm[u];
            acc[0] = fmaf(bf16_lo(vv[u].x), m, acc[0]);
            acc[1] = fmaf(bf16_hi(vv[u].x), m, acc[1]);
            acc[2] = fmaf(bf16_lo(vv[u].y), m, acc[2]);
            acc[3] = fmaf(bf16_hi(vv[u].y), m, acc[3]);
            acc[4] = fmaf(bf16_lo(vv[u].z), m, acc[4]);
            acc[5] = fmaf(bf16_hi(vv[u].z), m, acc[5]);
            acc[6] = fmaf(bf16_lo(vv[u].w), m, acc[6]);
            acc[7] = fmaf(bf16_hi(vv[u].w), m, acc[7]);
        }
    }
    #pragma unroll
    for (int t = 0; t < 8; ++t) {
        acc[t] += __shfl_xor(acc[t], 8);
        acc[t] += __shfl_xor(acc[t], 16);
        acc[t] += __shfl_xor(acc[t], 32);
    }
    const float di = dinv[node];
    const float4 bb0 = reinterpret_cast<const float4*>(b2)[li * 2];
    const float4 bb1 = reinterpret_cast<const float4*>(b2)[li * 2 + 1];
    float v0 = fmaf(di, acc[0], bb0.x);
    float v1 = fmaf(di, acc[1], bb0.y);
    float v2 = fmaf(di, acc[2], bb0.z);
    float v3 = fmaf(di, acc[3], bb0.w);
    float v4 = fmaf(di, acc[4], bb1.x);
    float v5 = fmaf(di, acc[5], bb1.y);
    float v6 = fmaf(di, acc[6], bb1.z);
    float v7 = fmaf(di, acc[7], bb1.w);
    float m = fmaxf(fmaxf(fmaxf(v0, v1), fmaxf(v2, v3)),
                    fmaxf(fmaxf(v4, v5), fmaxf(v6, v7)));
    #pragma unroll
    for (int o = 4; o > 0; o >>= 1) m = fmaxf(m, __shfl_xor(m, o));
    float es = expf(v0 - m) + expf(v1 - m) + expf(v2 - m) + expf(v3 - m)
             + expf(v4 - m) + expf(v5 - m) + expf(v6 - m) + expf(v7 - m);
    #pragma unroll
    for (int o = 4; o > 0; o >>= 1) es += __shfl_xor(es, o);
    if (s == 0) {
        const float lse = m + logf(es);
        float4 r0, r1;
        r0.x = v0 - lse; r0.y = v1 - lse; r0.z = v2 - lse; r0.w = v3 - lse;
        r1.x = v4 - lse; r1.y = v5 - lse; r1.z = v6 - lse; r1.w = v7 - lse;
        float4* op = reinterpret_cast<float4*>(out) + (size_t)node * 16 + li * 2;
        op[0] = r0;
        op[1] = r1;
    }
}

// ---------------------------------------------------------------------------
extern "C" void kernel_launch(void* const* d_in, const int* in_sizes, int n_in,
                              void* d_out, int out_size, void* d_ws, size_t ws_size,
                              hipStream_t stream) {
    const float* x  = (const float*)d_in[0];
    const int*   ei = (const int*)d_in[1];
    const float* W1 = (const float*)d_in[2];
    const float* b1 = (const float*)d_in[3];
    const float* W2 = (const float*)d_in[4];
    const float* b2 = (const float*)d_in[5];
    float* out = (float*)d_out;

    const int N = in_sizes[0] / 512;   // 100000
    const int E = in_sizes[1] / 2;     // 1600000
    const int* src = ei;
    const int* dst = ei + E;

    const int NBUCKET = (N + 255) >> BSHIFT;      // 391
    const int NB_E    = (E + EB - 1) / EB;        // 391
    const int T       = NBUCKET * NB_E;           // 152881
    const int nbb     = (T + 255) / 256;          // 598

    // workspace layout
    char* ws = (char*)d_ws;
    size_t o = 0;
    auto take = [&](size_t bytes) { char* p = ws + o; o = (o + bytes + 255) & ~(size_t)255; return p; };
    int*            cnt       = (int*)take((size_t)N * 4);
    int*            bsum      = (int*)take(1024 * 4);
    int*            row_start = (int*)take((size_t)N * 4);
    float*          dinv      = (float*)take((size_t)N * 4);
    int*            srcs      = (int*)take((size_t)E * 4);
    unsigned*       ebuf      = (unsigned*)take((size_t)E * 4);
    int*            counts    = (int*)take((size_t)T * 4);
    int*            offs      = (int*)take((size_t)T * 4);
    __hip_bfloat16* W1t       = (__hip_bfloat16*)take((size_t)128 * 512 * 2);
    __hip_bfloat16* W2t       = (__hip_bfloat16*)take((size_t)64 * 128 * 2);
    __hip_bfloat16* h         = (__hip_bfloat16*)take((size_t)N * 128 * 2);   // h' = dinv*h
    __hip_bfloat16* h2        = (__hip_bfloat16*)take((size_t)N * 64 * 2);    // h2' = dinv*h2

    const int mb = (N + 127) / 128;

    // ---- CSR build (bucketed counting sort) + weight convert ----
    hist_conv<<<NB_E + 288, 256, 0, stream>>>(dst, counts, W1, W2, W1t, W2t,
                                              NB_E, NBUCKET, E);
    scan_block_sums<<<nbb, 256, 0, stream>>>(counts, bsum, T);
    scan_offs<<<nbb, 256, 0, stream>>>(counts, bsum, offs, T);
    scatter_bucketed<<<NB_E, 256, 0, stream>>>(src, dst, offs, ebuf, NB_E, NBUCKET, E);
    bucket_csr<<<NBUCKET, 256, 0, stream>>>(ebuf, offs, row_start, cnt, dinv, srcs,
                                            NB_E, NBUCKET, N, E);

    // layer 1 + fused layer-2 transform
    gemm1_mfma<<<mb, 256, 0, stream>>>(x, W1t, dinv, h, N);
    agg1_fused<<<(N + 15) / 16, 256, 0, stream>>>(row_start, cnt, srcs, dinv,
                                                  (const uint4*)h, b1, W2t, h2, N);

    // layer-2 aggregation + log_softmax
    agg2_lsm8<<<(N + 3) / 4, 256, 0, stream>>>(row_start, cnt, srcs, dinv,
                                               (const uint4*)h2, b2, out, N);
}

// Round 13
// 224.060 us; speedup vs baseline: 1.0775x; 1.0775x over previous
//
#include <hip/hip_runtime.h>
#include <hip/hip_bf16.h>

// ---------------------------------------------------------------------------
// GCN 2-layer forward — round-9 configuration (best: 226.8 us) + merged
// hist+weight-convert launch.
//   Bucketed CSR (256-node buckets, EB=4096, no global atomics)
//   gemm1: MFMA bf16, 128x128 tile, LDS A+B staging, 2-barrier loop
//   agg1_fused: gather(16 rows in flight) + bias/relu + mini-GEMM2 + dinv
//   agg2_lsm8: gather + bias + log_softmax (8 slots x 8 lanes x uint4)
// ---------------------------------------------------------------------------

typedef float f32x4 __attribute__((ext_vector_type(4)));
typedef short bf16x8 __attribute__((ext_vector_type(8)));

__device__ inline float bf16_lo(unsigned int p) {
    return __uint_as_float((p & 0xffffu) << 16);
}
__device__ inline float bf16_hi(unsigned int p) {
    return __uint_as_float(p & 0xffff0000u);
}
__device__ inline unsigned short bf16_bits(float f) {
    __hip_bfloat16 b = __float2bfloat16(f);
    return *reinterpret_cast<unsigned short*>(&b);
}
__device__ inline unsigned int pack_bf16(float a, float b) {
    return (unsigned int)bf16_bits(a) | ((unsigned int)bf16_bits(b) << 16);
}

#define EB 4096            // edges per block in bucketing passes
#define BSHIFT 8           // bucket = dst >> 8  (256 nodes/bucket, 391 buckets)

// ------- pass 1: per-(block,bucket) histogram + weight convert (merged) ----
__global__ __launch_bounds__(256) void hist_conv(const int* __restrict__ dst,
                                                 int* __restrict__ counts,   // [NBUCKET][NB_E]
                                                 const float* __restrict__ W1,
                                                 const float* __restrict__ W2,
                                                 __hip_bfloat16* __restrict__ W1t,
                                                 __hip_bfloat16* __restrict__ W2t,
                                                 int NB_E, int NBUCKET, int E) {
    const int b = blockIdx.x;
    const int tid = threadIdx.x;
    if (b < NB_E) {
        __shared__ int hist[512];
        for (int i = tid; i < NBUCKET; i += 256) hist[i] = 0;
        __syncthreads();
        const int e0 = b * EB;
        const int e1 = min(e0 + EB, E);
        for (int e = e0 + tid; e < e1; e += 256)
            atomicAdd(&hist[dst[e] >> BSHIFT], 1);
        __syncthreads();
        for (int i = tid; i < NBUCKET; i += 256)
            counts[(size_t)i * NB_E + b] = hist[i];
    } else if (b < NB_E + 256) {
        const int idx = (b - NB_E) * 256 + tid;        // 0 .. 128*512-1
        const int c = idx >> 9, k = idx & 511;
        W1t[idx] = __float2bfloat16(W1[k * 128 + c]);
    } else {
        const int idx = (b - NB_E - 256) * 256 + tid;  // 0 .. 64*128-1
        const int c = idx >> 7, k = idx & 127;
        W2t[idx] = __float2bfloat16(W2[k * 64 + c]);
    }
}

// ---------------- scan machinery (2-level, exclusive) ----------------
__global__ __launch_bounds__(256) void scan_block_sums(const int* __restrict__ v, int* __restrict__ bsum, int T) {
    __shared__ int s[256];
    int i = blockIdx.x * 256 + threadIdx.x;
    s[threadIdx.x] = (i < T) ? v[i] : 0;
    __syncthreads();
    for (int off = 128; off > 0; off >>= 1) {
        if (threadIdx.x < off) s[threadIdx.x] += s[threadIdx.x + off];
        __syncthreads();
    }
    if (threadIdx.x == 0) bsum[blockIdx.x] = s[0];
}

// fused: block base = sum of raw bsum[0..bid-1], then local exclusive scan
__global__ __launch_bounds__(256) void scan_offs(const int* __restrict__ v, const int* __restrict__ bsum,
                                                 int* __restrict__ offs, int T) {
    __shared__ int s[256];
    __shared__ int base_s;
    const int tid = threadIdx.x;
    int p = 0;
    for (int i = tid; i < (int)blockIdx.x; i += 256) p += bsum[i];
    s[tid] = p;
    __syncthreads();
    for (int off = 128; off > 0; off >>= 1) {
        if (tid < off) s[tid] += s[tid + off];
        __syncthreads();
    }
    if (tid == 0) base_s = s[0];
    __syncthreads();
    const int base = base_s;
    __syncthreads();
    int i = blockIdx.x * 256 + tid;
    int x = (i < T) ? v[i] : 0;
    s[tid] = x;
    __syncthreads();
    for (int off = 1; off < 256; off <<= 1) {
        int t = (tid >= off) ? s[tid - off] : 0;
        __syncthreads();
        s[tid] += t;
        __syncthreads();
    }
    if (i < T) offs[i] = s[tid] - x + base;
}

// ------ pass 3: bucket-major edge materialization (packed 4B records) ------
// record = src (bits 0..23) | local_dst (bits 24..31)
__global__ __launch_bounds__(256) void scatter_bucketed(const int* __restrict__ src,
                                                        const int* __restrict__ dst,
                                                        const int* __restrict__ offs,  // [NBUCKET][NB_E]
                                                        unsigned* __restrict__ ebuf,
                                                        int NB_E, int NBUCKET, int E) {
    __shared__ int lcur[512];
    const int tid = threadIdx.x;
    for (int i = tid; i < NBUCKET; i += 256)
        lcur[i] = offs[(size_t)i * NB_E + blockIdx.x];
    __syncthreads();
    const int e0 = blockIdx.x * EB;
    const int e1 = min(e0 + EB, E);
    for (int e = e0 + tid; e < e1; e += 256) {
        const int d = dst[e];
        const int s = src[e];
        const int pos = atomicAdd(&lcur[d >> BSHIFT], 1);
        ebuf[pos] = (unsigned)s | ((unsigned)(d & 255) << 24);
    }
}

// ---------------- pass 4: per-bucket CSR finalize (all LDS) ----------------
__global__ __launch_bounds__(256) void bucket_csr(const unsigned* __restrict__ ebuf,
                                                  const int* __restrict__ offs,
                                                  int* __restrict__ row_start,
                                                  int* __restrict__ cnt,
                                                  float* __restrict__ dinv,
                                                  int* __restrict__ srcs,
                                                  int NB_E, int NBUCKET, int N, int E) {
    __shared__ int lcnt[256];
    __shared__ int lscan[256];
    __shared__ int lcur[256];
    const int tid = threadIdx.x;
    const int b = blockIdx.x;
    const int node_base = b << BSHIFT;
    const int ebeg = offs[(size_t)b * NB_E];
    const int eend = (b + 1 < NBUCKET) ? offs[(size_t)(b + 1) * NB_E] : E;

    lcnt[tid] = 0;
    __syncthreads();
    for (int e = ebeg + tid; e < eend; e += 256)
        atomicAdd(&lcnt[ebuf[e] >> 24], 1);
    __syncthreads();

    int v = lcnt[tid];
    lscan[tid] = v;
    __syncthreads();
    for (int off = 1; off < 256; off <<= 1) {
        int t = (tid >= off) ? lscan[tid - off] : 0;
        __syncthreads();
        lscan[tid] += t;
        __syncthreads();
    }
    const int excl = lscan[tid] - v;

    const int node = node_base + tid;
    if (node < N) {
        row_start[node] = ebeg + excl;
        cnt[node]       = v;
        dinv[node]      = rsqrtf((float)(v + 1));
    }
    lcur[tid] = excl;
    __syncthreads();

    for (int e = ebeg + tid; e < eend; e += 256) {
        const unsigned p = ebuf[e];
        const int pos = ebeg + atomicAdd(&lcur[p >> 24], 1);
        srcs[pos] = (int)(p & 0xFFFFFFu);
    }
}

// ---------------- GEMM1: h' = dinv * (x @ W1)  (MFMA bf16) ----------------
// Round-9 structure: LDS A+B staging, 2 barriers per K-step (best measured).
__global__ __launch_bounds__(256) void gemm1_mfma(const float* __restrict__ A,          // [M][512]
                                                  const __hip_bfloat16* __restrict__ Bt, // [128][512]
                                                  const float* __restrict__ dinv,
                                                  __hip_bfloat16* __restrict__ C,        // [M][128]
                                                  int M) {
    __shared__ __hip_bfloat16 As[128 * 64];
    __shared__ __hip_bfloat16 Bs[128 * 64];
    __shared__ float sdinv[128];
    const int tid  = threadIdx.x;
    const int lane = tid & 63;
    const int wid  = tid >> 6;
    const int wr   = wid >> 1, wc = wid & 1;
    const int g    = lane >> 4, l15 = lane & 15;
    const int row0 = blockIdx.x * 128;

    if (tid < 128) {
        int gr = row0 + tid;
        sdinv[tid] = dinv[gr < M ? gr : M - 1];
    }

    f32x4 acc[4][4] = {};

    for (int kt = 0; kt < 8; ++kt) {
        #pragma unroll
        for (int it = 0; it < 8; ++it) {
            const int r = it * 16 + (tid >> 4);
            const int k = (tid & 15) * 4;
            int gr = row0 + r; if (gr >= M) gr = M - 1;
            const f32x4 v = *reinterpret_cast<const f32x4*>(A + (size_t)gr * 512 + kt * 64 + k);
            ushort4 p;
            p.x = bf16_bits(v.x); p.y = bf16_bits(v.y);
            p.z = bf16_bits(v.z); p.w = bf16_bits(v.w);
            const int kw = k ^ ((r & 7) << 3);
            *reinterpret_cast<ushort4*>(&As[r * 64 + kw]) = p;
        }
        #pragma unroll
        for (int it = 0; it < 4; ++it) {
            const int c = it * 32 + (tid >> 3);
            const int k = (tid & 7) * 8;
            const uint4 v = *reinterpret_cast<const uint4*>(Bt + (size_t)c * 512 + kt * 64 + k);
            const int kw = k ^ ((c & 7) << 3);
            *reinterpret_cast<uint4*>(&Bs[c * 64 + kw]) = v;
        }
        __syncthreads();
        #pragma unroll
        for (int kk = 0; kk < 2; ++kk) {
            bf16x8 af[4], bfr[4];
            const int k0 = kk * 32 + g * 8;
            #pragma unroll
            for (int i = 0; i < 4; ++i) {
                const int r = wr * 64 + i * 16 + l15;
                af[i] = *reinterpret_cast<const bf16x8*>(&As[r * 64 + (k0 ^ ((r & 7) << 3))]);
            }
            #pragma unroll
            for (int j = 0; j < 4; ++j) {
                const int c = wc * 64 + j * 16 + l15;
                bfr[j] = *reinterpret_cast<const bf16x8*>(&Bs[c * 64 + (k0 ^ ((c & 7) << 3))]);
            }
            #pragma unroll
            for (int i = 0; i < 4; ++i)
                #pragma unroll
                for (int j = 0; j < 4; ++j)
                    acc[i][j] = __builtin_amdgcn_mfma_f32_16x16x32_bf16(af[i], bfr[j], acc[i][j], 0, 0, 0);
        }
        __syncthreads();
    }
    #pragma unroll
    for (int i = 0; i < 4; ++i) {
        #pragma unroll
        for (int q = 0; q < 4; ++q) {
            const int lr  = wr * 64 + i * 16 + g * 4 + q;
            const int row = row0 + lr;
            if (row < M) {
                const float dv = sdinv[lr];
                #pragma unroll
                for (int j = 0; j < 4; ++j)
                    C[(size_t)row * 128 + wc * 64 + j * 16 + l15] = __float2bfloat16(acc[i][j][q] * dv);
            }
        }
    }
}

// ---- fused agg1 + bias + relu + (r @ W2) + dinv scale -> h2' (bf16) ------
// Block: 256 thr = 4 waves = 16 nodes (each wave handles 4 nodes serially).
// Gather: predicated-clamped, 16 rows in flight per wave per iteration.
__global__ __launch_bounds__(256) void agg1_fused(const int* __restrict__ row_start,
                                                  const int* __restrict__ cnt,
                                                  const int* __restrict__ srcs,
                                                  const float* __restrict__ dinv,
                                                  const uint4* __restrict__ h4,   // [N][16] (128 bf16)
                                                  const float* __restrict__ b1,
                                                  const __hip_bfloat16* __restrict__ W2t, // [64][128]
                                                  __hip_bfloat16* __restrict__ h2,        // [N][64]
                                                  int N) {
    __shared__ __hip_bfloat16 w2s[64 * 128];   // 16 KB, swizzled
    __shared__ __hip_bfloat16 rs[16 * 128];    // 4 KB, all 16 rows valid
    const int tid  = threadIdx.x;
    const int w    = tid >> 6;
    const int lane = tid & 63;
    const int s    = lane >> 4, li = lane & 15;

    // stage W2t into LDS with swizzle: (c,k) -> c*128 + (k^((c&15)<<3))
    {
        const uint4* s4 = reinterpret_cast<const uint4*>(W2t);
        for (int i = tid; i < 1024; i += 256) {
            const int c = i >> 4;
            const int k = (i & 15) * 8;
            const uint4 v = s4[i];
            *reinterpret_cast<uint4*>(&w2s[c * 128 + (k ^ ((c & 15) << 3))]) = v;
        }
    }

    const int base = blockIdx.x * 16;

    #pragma unroll 1
    for (int q = 0; q < 4; ++q) {
        const int node = base + w * 4 + q;
        const bool active = node < N;

        float acc[8] = {};

        int beg = 0, num = 0;
        if (active) { beg = row_start[node]; num = cnt[node]; }
        if (active && s == 0) {   // self-loop once
            const uint4 v = h4[(size_t)node * 16 + li];
            acc[0] += bf16_lo(v.x); acc[1] += bf16_hi(v.x);
            acc[2] += bf16_lo(v.y); acc[3] += bf16_hi(v.y);
            acc[4] += bf16_lo(v.z); acc[5] += bf16_hi(v.z);
            acc[6] += bf16_lo(v.w); acc[7] += bf16_hi(v.w);
        }

        // predicated gather: 16 edges / iteration, no divergent tail
        for (int j = 0; j < num; j += 16) {
            uint4 vv[4];
            float mm[4];
            #pragma unroll
            for (int u = 0; u < 4; ++u) {
                const int jj = j + u * 4 + s;
                mm[u] = (jj < num) ? 1.0f : 0.0f;
                const int idx = (jj < num) ? jj : (num - 1);
                vv[u] = h4[(size_t)srcs[beg + idx] * 16 + li];
            }
            #pragma unroll
            for (int u = 0; u < 4; ++u) {
                const float m = mm[u];
                acc[0] = fmaf(bf16_lo(vv[u].x), m, acc[0]);
                acc[1] = fmaf(bf16_hi(vv[u].x), m, acc[1]);
                acc[2] = fmaf(bf16_lo(vv[u].y), m, acc[2]);
                acc[3] = fmaf(bf16_hi(vv[u].y), m, acc[3]);
                acc[4] = fmaf(bf16_lo(vv[u].z), m, acc[4]);
                acc[5] = fmaf(bf16_hi(vv[u].z), m, acc[5]);
                acc[6] = fmaf(bf16_lo(vv[u].w), m, acc[6]);
                acc[7] = fmaf(bf16_hi(vv[u].w), m, acc[7]);
            }
        }
        #pragma unroll
        for (int t = 0; t < 8; ++t) {
            acc[t] += __shfl_xor(acc[t], 16);
            acc[t] += __shfl_xor(acc[t], 32);
        }
        if (active && s == 0) {
            const float di = dinv[node];
            const float4 bb0 = reinterpret_cast<const float4*>(b1)[li * 2];
            const float4 bb1 = reinterpret_cast<const float4*>(b1)[li * 2 + 1];
            const float r0 = fmaxf(fmaf(di, acc[0], bb0.x), 0.0f);
            const float r1 = fmaxf(fmaf(di, acc[1], bb0.y), 0.0f);
            const float r2 = fmaxf(fmaf(di, acc[2], bb0.z), 0.0f);
            const float r3 = fmaxf(fmaf(di, acc[3], bb0.w), 0.0f);
            const float r4 = fmaxf(fmaf(di, acc[4], bb1.x), 0.0f);
            const float r5 = fmaxf(fmaf(di, acc[5], bb1.y), 0.0f);
            const float r6 = fmaxf(fmaf(di, acc[6], bb1.z), 0.0f);
            const float r7 = fmaxf(fmaf(di, acc[7], bb1.w), 0.0f);
            uint4 o;
            o.x = pack_bf16(r0, r1); o.y = pack_bf16(r2, r3);
            o.z = pack_bf16(r4, r5); o.w = pack_bf16(r6, r7);
            const int row = w * 4 + q;
            const int k = li * 8;
            *reinterpret_cast<uint4*>(&rs[row * 128 + (k ^ ((row & 15) << 3))]) = o;
        }
    }
    __syncthreads();   // uniform: no early returns above

    // full mini-GEMM: C[0..15][w*16 .. w*16+15], K=128  (lane reads A row li)
    f32x4 oacc = {};
    #pragma unroll
    for (int kk = 0; kk < 4; ++kk) {
        const int k0 = kk * 32 + s * 8;
        const bf16x8 af = *reinterpret_cast<const bf16x8*>(&rs[li * 128 + (k0 ^ ((li & 15) << 3))]);
        const int c = w * 16 + li;
        const bf16x8 bfr = *reinterpret_cast<const bf16x8*>(&w2s[c * 128 + (k0 ^ ((c & 15) << 3))]);
        oacc = __builtin_amdgcn_mfma_f32_16x16x32_bf16(af, bfr, oacc, 0, 0, 0);
    }
    // D layout: row = s*4 + reg, col = li within wave's 16-col block
    #pragma unroll
    for (int q = 0; q < 4; ++q) {
        const int nd = base + s * 4 + q;
        if (nd < N) {
            const float dv = dinv[nd];
            h2[(size_t)nd * 64 + w * 16 + li] = __float2bfloat16(oacc[q] * dv);
        }
    }
}

// --- layer-2 agg + bias + log_softmax: 8 slots x 8 lanes x uint4 (full row) -
__global__ __launch_bounds__(256) void agg2_lsm8(const int* __restrict__ row_start,
                                                 const int* __restrict__ cnt,
                                                 const int* __restrict__ srcs,
                                                 const float* __restrict__ dinv,
                                                 const uint4* __restrict__ h2r,  // [N][8] (64 bf16)
                                                 const float* __restrict__ b2,
                                                 float* __restrict__ out, int N) {
    int node = blockIdx.x * 4 + (threadIdx.x >> 6);
    if (node >= N) return;
    const int lane = threadIdx.x & 63;
    const int s = lane >> 3, li = lane & 7;

    float acc[8] = {};
    if (s == 0) {   // self-loop
        const uint4 v = h2r[(size_t)node * 8 + li];
        acc[0] += bf16_lo(v.x); acc[1] += bf16_hi(v.x);
        acc[2] += bf16_lo(v.y); acc[3] += bf16_hi(v.y);
        acc[4] += bf16_lo(v.z); acc[5] += bf16_hi(v.z);
        acc[6] += bf16_lo(v.w); acc[7] += bf16_hi(v.w);
    }
    const int beg = row_start[node];
    const int num = cnt[node];
    for (int j = 0; j < num; j += 16) {
        uint4 vv[2];
        float mm[2];
        #pragma unroll
        for (int u = 0; u < 2; ++u) {
            const int jj = j + u * 8 + s;
            mm[u] = (jj < num) ? 1.0f : 0.0f;
            const int idx = (jj < num) ? jj : (num - 1);
            vv[u] = h2r[(size_t)srcs[beg + idx] * 8 + li];
        }
        #pragma unroll
        for (int u = 0; u < 2; ++u) {
            const float m = mm[u];
            acc[0] = fmaf(bf16_lo(vv[u].x), m, acc[0]);
            acc[1] = fmaf(bf16_hi(vv[u].x), m, acc[1]);
            acc[2] = fmaf(bf16_lo(vv[u].y), m, acc[2]);
            acc[3] = fmaf(bf16_hi(vv[u].y), m, acc[3]);
            acc[4] = fmaf(bf16_lo(vv[u].z), m, acc[4]);
            acc[5] = fmaf(bf16_hi(vv[u].z), m, acc[5]);
            acc[6] = fmaf(bf16_lo(vv[u].w), m, acc[6]);
            acc[7] = fmaf(bf16_hi(vv[u].w), m, acc[7]);
        }
    }
    #pragma unroll
    for (int t = 0; t < 8; ++t) {
        acc[t] += __shfl_xor(acc[t], 8);
        acc[t] += __shfl_xor(acc[t], 16);
        acc[t] += __shfl_xor(acc[t], 32);
    }
    const float di = dinv[node];
    const float4 bb0 = reinterpret_cast<const float4*>(b2)[li * 2];
    const float4 bb1 = reinterpret_cast<const float4*>(b2)[li * 2 + 1];
    float v0 = fmaf(di, acc[0], bb0.x);
    float v1 = fmaf(di, acc[1], bb0.y);
    float v2 = fmaf(di, acc[2], bb0.z);
    float v3 = fmaf(di, acc[3], bb0.w);
    float v4 = fmaf(di, acc[4], bb1.x);
    float v5 = fmaf(di, acc[5], bb1.y);
    float v6 = fmaf(di, acc[6], bb1.z);
    float v7 = fmaf(di, acc[7], bb1.w);
    float m = fmaxf(fmaxf(fmaxf(v0, v1), fmaxf(v2, v3)),
                    fmaxf(fmaxf(v4, v5), fmaxf(v6, v7)));
    #pragma unroll
    for (int o = 4; o > 0; o >>= 1) m = fmaxf(m, __shfl_xor(m, o));
    float es = expf(v0 - m) + expf(v1 - m) + expf(v2 - m) + expf(v3 - m)
             + expf(v4 - m) + expf(v5 - m) + expf(v6 - m) + expf(v7 - m);
    #pragma unroll
    for (int o = 4; o > 0; o >>= 1) es += __shfl_xor(es, o);
    if (s == 0) {
        const float lse = m + logf(es);
        float4 r0, r1;
        r0.x = v0 - lse; r0.y = v1 - lse; r0.z = v2 - lse; r0.w = v3 - lse;
        r1.x = v4 - lse; r1.y = v5 - lse; r1.z = v6 - lse; r1.w = v7 - lse;
        float4* op = reinterpret_cast<float4*>(out) + (size_t)node * 16 + li * 2;
        op[0] = r0;
        op[1] = r1;
    }
}

// ---------------------------------------------------------------------------
extern "C" void kernel_launch(void* const* d_in, const int* in_sizes, int n_in,
                              void* d_out, int out_size, void* d_ws, size_t ws_size,
                              hipStream_t stream) {
    const float* x  = (const float*)d_in[0];
    const int*   ei = (const int*)d_in[1];
    const float* W1 = (const float*)d_in[2];
    const float* b1 = (const float*)d_in[3];
    const float* W2 = (const float*)d_in[4];
    const float* b2 = (const float*)d_in[5];
    float* out = (float*)d_out;

    const int N = in_sizes[0] / 512;   // 100000
    const int E = in_sizes[1] / 2;     // 1600000
    const int* src = ei;
    const int* dst = ei + E;

    const int NBUCKET = (N + 255) >> BSHIFT;      // 391
    const int NB_E    = (E + EB - 1) / EB;        // 391
    const int T       = NBUCKET * NB_E;           // 152881
    const int nbb     = (T + 255) / 256;          // 598

    // workspace layout
    char* ws = (char*)d_ws;
    size_t o = 0;
    auto take = [&](size_t bytes) { char* p = ws + o; o = (o + bytes + 255) & ~(size_t)255; return p; };
    int*            cnt       = (int*)take((size_t)N * 4);
    int*            bsum      = (int*)take(1024 * 4);
    int*            row_start = (int*)take((size_t)N * 4);
    float*          dinv      = (float*)take((size_t)N * 4);
    int*            srcs      = (int*)take((size_t)E * 4);
    unsigned*       ebuf      = (unsigned*)take((size_t)E * 4);
    int*            counts    = (int*)take((size_t)T * 4);
    int*            offs      = (int*)take((size_t)T * 4);
    __hip_bfloat16* W1t       = (__hip_bfloat16*)take((size_t)128 * 512 * 2);
    __hip_bfloat16* W2t       = (__hip_bfloat16*)take((size_t)64 * 128 * 2);
    __hip_bfloat16* h         = (__hip_bfloat16*)take((size_t)N * 128 * 2);   // h' = dinv*h
    __hip_bfloat16* h2        = (__hip_bfloat16*)take((size_t)N * 64 * 2);    // h2' = dinv*h2

    const int mb = (N + 127) / 128;

    // ---- CSR build (bucketed counting sort) + weight convert ----
    hist_conv<<<NB_E + 288, 256, 0, stream>>>(dst, counts, W1, W2, W1t, W2t,
                                              NB_E, NBUCKET, E);
    scan_block_sums<<<nbb, 256, 0, stream>>>(counts, bsum, T);
    scan_offs<<<nbb, 256, 0, stream>>>(counts, bsum, offs, T);
    scatter_bucketed<<<NB_E, 256, 0, stream>>>(src, dst, offs, ebuf, NB_E, NBUCKET, E);
    bucket_csr<<<NBUCKET, 256, 0, stream>>>(ebuf, offs, row_start, cnt, dinv, srcs,
                                            NB_E, NBUCKET, N, E);

    // layer 1 + fused layer-2 transform
    gemm1_mfma<<<mb, 256, 0, stream>>>(x, W1t, dinv, h, N);
    agg1_fused<<<(N + 15) / 16, 256, 0, stream>>>(row_start, cnt, srcs, dinv,
                                                  (const uint4*)h, b1, W2t, h2, N);

    // layer-2 aggregation + log_softmax
    agg2_lsm8<<<(N + 3) / 4, 256, 0, stream>>>(row_start, cnt, srcs, dinv,
                                               (const uint4*)h2, b2, out, N);
}

// Round 14
// 223.284 us; speedup vs baseline: 1.0813x; 1.0035x over previous
//
#include <hip/hip_runtime.h>
#include <hip/hip_bf16.h>

// ---------------------------------------------------------------------------
// GCN 2-layer forward — round-13 base (224 us) with gemm1 tile 128x128 ->
// 64x128 (1563 blocks: finer tail, higher occupancy for the memory-bound
// stream; B re-reads are L2-absorbed).
//   Bucketed CSR (256-node buckets, EB=4096, no global atomics)
//   agg1_fused: gather(16 rows in flight) + bias/relu + mini-GEMM2 + dinv
//   agg2_lsm8: gather + bias + log_softmax (8 slots x 8 lanes x uint4)
// ---------------------------------------------------------------------------

typedef float f32x4 __attribute__((ext_vector_type(4)));
typedef short bf16x8 __attribute__((ext_vector_type(8)));

__device__ inline float bf16_lo(unsigned int p) {
    return __uint_as_float((p & 0xffffu) << 16);
}
__device__ inline float bf16_hi(unsigned int p) {
    return __uint_as_float(p & 0xffff0000u);
}
__device__ inline unsigned short bf16_bits(float f) {
    __hip_bfloat16 b = __float2bfloat16(f);
    return *reinterpret_cast<unsigned short*>(&b);
}
__device__ inline unsigned int pack_bf16(float a, float b) {
    return (unsigned int)bf16_bits(a) | ((unsigned int)bf16_bits(b) << 16);
}

#define EB 4096            // edges per block in bucketing passes
#define BSHIFT 8           // bucket = dst >> 8  (256 nodes/bucket, 391 buckets)

// ------- pass 1: per-(block,bucket) histogram + weight convert (merged) ----
__global__ __launch_bounds__(256) void hist_conv(const int* __restrict__ dst,
                                                 int* __restrict__ counts,   // [NBUCKET][NB_E]
                                                 const float* __restrict__ W1,
                                                 const float* __restrict__ W2,
                                                 __hip_bfloat16* __restrict__ W1t,
                                                 __hip_bfloat16* __restrict__ W2t,
                                                 int NB_E, int NBUCKET, int E) {
    const int b = blockIdx.x;
    const int tid = threadIdx.x;
    if (b < NB_E) {
        __shared__ int hist[512];
        for (int i = tid; i < NBUCKET; i += 256) hist[i] = 0;
        __syncthreads();
        const int e0 = b * EB;
        const int e1 = min(e0 + EB, E);
        for (int e = e0 + tid; e < e1; e += 256)
            atomicAdd(&hist[dst[e] >> BSHIFT], 1);
        __syncthreads();
        for (int i = tid; i < NBUCKET; i += 256)
            counts[(size_t)i * NB_E + b] = hist[i];
    } else if (b < NB_E + 256) {
        const int idx = (b - NB_E) * 256 + tid;        // 0 .. 128*512-1
        const int c = idx >> 9, k = idx & 511;
        W1t[idx] = __float2bfloat16(W1[k * 128 + c]);
    } else {
        const int idx = (b - NB_E - 256) * 256 + tid;  // 0 .. 64*128-1
        const int c = idx >> 7, k = idx & 127;
        W2t[idx] = __float2bfloat16(W2[k * 64 + c]);
    }
}

// ---------------- scan machinery (2-level, exclusive) ----------------
__global__ __launch_bounds__(256) void scan_block_sums(const int* __restrict__ v, int* __restrict__ bsum, int T) {
    __shared__ int s[256];
    int i = blockIdx.x * 256 + threadIdx.x;
    s[threadIdx.x] = (i < T) ? v[i] : 0;
    __syncthreads();
    for (int off = 128; off > 0; off >>= 1) {
        if (threadIdx.x < off) s[threadIdx.x] += s[threadIdx.x + off];
        __syncthreads();
    }
    if (threadIdx.x == 0) bsum[blockIdx.x] = s[0];
}

// fused: block base = sum of raw bsum[0..bid-1], then local exclusive scan
__global__ __launch_bounds__(256) void scan_offs(const int* __restrict__ v, const int* __restrict__ bsum,
                                                 int* __restrict__ offs, int T) {
    __shared__ int s[256];
    __shared__ int base_s;
    const int tid = threadIdx.x;
    int p = 0;
    for (int i = tid; i < (int)blockIdx.x; i += 256) p += bsum[i];
    s[tid] = p;
    __syncthreads();
    for (int off = 128; off > 0; off >>= 1) {
        if (tid < off) s[tid] += s[tid + off];
        __syncthreads();
    }
    if (tid == 0) base_s = s[0];
    __syncthreads();
    const int base = base_s;
    __syncthreads();
    int i = blockIdx.x * 256 + tid;
    int x = (i < T) ? v[i] : 0;
    s[tid] = x;
    __syncthreads();
    for (int off = 1; off < 256; off <<= 1) {
        int t = (tid >= off) ? s[tid - off] : 0;
        __syncthreads();
        s[tid] += t;
        __syncthreads();
    }
    if (i < T) offs[i] = s[tid] - x + base;
}

// ------ pass 3: bucket-major edge materialization (packed 4B records) ------
// record = src (bits 0..23) | local_dst (bits 24..31)
__global__ __launch_bounds__(256) void scatter_bucketed(const int* __restrict__ src,
                                                        const int* __restrict__ dst,
                                                        const int* __restrict__ offs,  // [NBUCKET][NB_E]
                                                        unsigned* __restrict__ ebuf,
                                                        int NB_E, int NBUCKET, int E) {
    __shared__ int lcur[512];
    const int tid = threadIdx.x;
    for (int i = tid; i < NBUCKET; i += 256)
        lcur[i] = offs[(size_t)i * NB_E + blockIdx.x];
    __syncthreads();
    const int e0 = blockIdx.x * EB;
    const int e1 = min(e0 + EB, E);
    for (int e = e0 + tid; e < e1; e += 256) {
        const int d = dst[e];
        const int s = src[e];
        const int pos = atomicAdd(&lcur[d >> BSHIFT], 1);
        ebuf[pos] = (unsigned)s | ((unsigned)(d & 255) << 24);
    }
}

// ---------------- pass 4: per-bucket CSR finalize (all LDS) ----------------
__global__ __launch_bounds__(256) void bucket_csr(const unsigned* __restrict__ ebuf,
                                                  const int* __restrict__ offs,
                                                  int* __restrict__ row_start,
                                                  int* __restrict__ cnt,
                                                  float* __restrict__ dinv,
                                                  int* __restrict__ srcs,
                                                  int NB_E, int NBUCKET, int N, int E) {
    __shared__ int lcnt[256];
    __shared__ int lscan[256];
    __shared__ int lcur[256];
    const int tid = threadIdx.x;
    const int b = blockIdx.x;
    const int node_base = b << BSHIFT;
    const int ebeg = offs[(size_t)b * NB_E];
    const int eend = (b + 1 < NBUCKET) ? offs[(size_t)(b + 1) * NB_E] : E;

    lcnt[tid] = 0;
    __syncthreads();
    for (int e = ebeg + tid; e < eend; e += 256)
        atomicAdd(&lcnt[ebuf[e] >> 24], 1);
    __syncthreads();

    int v = lcnt[tid];
    lscan[tid] = v;
    __syncthreads();
    for (int off = 1; off < 256; off <<= 1) {
        int t = (tid >= off) ? lscan[tid - off] : 0;
        __syncthreads();
        lscan[tid] += t;
        __syncthreads();
    }
    const int excl = lscan[tid] - v;

    const int node = node_base + tid;
    if (node < N) {
        row_start[node] = ebeg + excl;
        cnt[node]       = v;
        dinv[node]      = rsqrtf((float)(v + 1));
    }
    lcur[tid] = excl;
    __syncthreads();

    for (int e = ebeg + tid; e < eend; e += 256) {
        const unsigned p = ebuf[e];
        const int pos = ebeg + atomicAdd(&lcur[p >> 24], 1);
        srcs[pos] = (int)(p & 0xFFFFFFu);
    }
}

// ---------------- GEMM1: h' = dinv * (x @ W1)  (MFMA bf16) ----------------
// 64x128 tile, 1563 blocks. LDS A+B staging, 2 barriers per K-step.
// 4 waves in 2x2: each wave owns a 32x64 sub-tile (acc 2x4 frags).
__global__ __launch_bounds__(256) void gemm1_mfma(const float* __restrict__ A,          // [M][512]
                                                  const __hip_bfloat16* __restrict__ Bt, // [128][512]
                                                  const float* __restrict__ dinv,
                                                  __hip_bfloat16* __restrict__ C,        // [M][128]
                                                  int M) {
    __shared__ __hip_bfloat16 As[64 * 64];     // 8 KB
    __shared__ __hip_bfloat16 Bs[128 * 64];    // 16 KB
    __shared__ float sdinv[64];
    const int tid  = threadIdx.x;
    const int lane = tid & 63;
    const int wid  = tid >> 6;
    const int wr   = wid >> 1, wc = wid & 1;   // 2x2 waves over 64x128
    const int g    = lane >> 4, l15 = lane & 15;
    const int row0 = blockIdx.x * 64;

    if (tid < 64) {
        int gr = row0 + tid;
        sdinv[tid] = dinv[gr < M ? gr : M - 1];
    }

    f32x4 acc[2][4] = {};

    for (int kt = 0; kt < 8; ++kt) {
        // stage A: 64 rows x 64 k, f32 -> bf16 (4 iters x 16 rows)
        #pragma unroll
        for (int it = 0; it < 4; ++it) {
            const int r = it * 16 + (tid >> 4);
            const int k = (tid & 15) * 4;
            int gr = row0 + r; if (gr >= M) gr = M - 1;
            const f32x4 v = *reinterpret_cast<const f32x4*>(A + (size_t)gr * 512 + kt * 64 + k);
            ushort4 p;
            p.x = bf16_bits(v.x); p.y = bf16_bits(v.y);
            p.z = bf16_bits(v.z); p.w = bf16_bits(v.w);
            const int kw = k ^ ((r & 7) << 3);
            *reinterpret_cast<ushort4*>(&As[r * 64 + kw]) = p;
        }
        // stage B: 128 cols x 64 k (4 iters x 32 cols)
        #pragma unroll
        for (int it = 0; it < 4; ++it) {
            const int c = it * 32 + (tid >> 3);
            const int k = (tid & 7) * 8;
            const uint4 v = *reinterpret_cast<const uint4*>(Bt + (size_t)c * 512 + kt * 64 + k);
            const int kw = k ^ ((c & 7) << 3);
            *reinterpret_cast<uint4*>(&Bs[c * 64 + kw]) = v;
        }
        __syncthreads();
        #pragma unroll
        for (int kk = 0; kk < 2; ++kk) {
            bf16x8 af[2], bfr[4];
            const int k0 = kk * 32 + g * 8;
            #pragma unroll
            for (int i = 0; i < 2; ++i) {
                const int r = wr * 32 + i * 16 + l15;
                af[i] = *reinterpret_cast<const bf16x8*>(&As[r * 64 + (k0 ^ ((r & 7) << 3))]);
            }
            #pragma unroll
            for (int j = 0; j < 4; ++j) {
                const int c = wc * 64 + j * 16 + l15;
                bfr[j] = *reinterpret_cast<const bf16x8*>(&Bs[c * 64 + (k0 ^ ((c & 7) << 3))]);
            }
            #pragma unroll
            for (int i = 0; i < 2; ++i)
                #pragma unroll
                for (int j = 0; j < 4; ++j)
                    acc[i][j] = __builtin_amdgcn_mfma_f32_16x16x32_bf16(af[i], bfr[j], acc[i][j], 0, 0, 0);
        }
        __syncthreads();
    }
    #pragma unroll
    for (int i = 0; i < 2; ++i) {
        #pragma unroll
        for (int q = 0; q < 4; ++q) {
            const int lr  = wr * 32 + i * 16 + g * 4 + q;
            const int row = row0 + lr;
            if (row < M) {
                const float dv = sdinv[lr];
                #pragma unroll
                for (int j = 0; j < 4; ++j)
                    C[(size_t)row * 128 + wc * 64 + j * 16 + l15] = __float2bfloat16(acc[i][j][q] * dv);
            }
        }
    }
}

// ---- fused agg1 + bias + relu + (r @ W2) + dinv scale -> h2' (bf16) ------
// Block: 256 thr = 4 waves = 16 nodes (each wave handles 4 nodes serially).
// Gather: predicated-clamped, 16 rows in flight per wave per iteration.
__global__ __launch_bounds__(256) void agg1_fused(const int* __restrict__ row_start,
                                                  const int* __restrict__ cnt,
                                                  const int* __restrict__ srcs,
                                                  const float* __restrict__ dinv,
                                                  const uint4* __restrict__ h4,   // [N][16] (128 bf16)
                                                  const float* __restrict__ b1,
                                                  const __hip_bfloat16* __restrict__ W2t, // [64][128]
                                                  __hip_bfloat16* __restrict__ h2,        // [N][64]
                                                  int N) {
    __shared__ __hip_bfloat16 w2s[64 * 128];   // 16 KB, swizzled
    __shared__ __hip_bfloat16 rs[16 * 128];    // 4 KB, all 16 rows valid
    const int tid  = threadIdx.x;
    const int w    = tid >> 6;
    const int lane = tid & 63;
    const int s    = lane >> 4, li = lane & 15;

    // stage W2t into LDS with swizzle: (c,k) -> c*128 + (k^((c&15)<<3))
    {
        const uint4* s4 = reinterpret_cast<const uint4*>(W2t);
        for (int i = tid; i < 1024; i += 256) {
            const int c = i >> 4;
            const int k = (i & 15) * 8;
            const uint4 v = s4[i];
            *reinterpret_cast<uint4*>(&w2s[c * 128 + (k ^ ((c & 15) << 3))]) = v;
        }
    }

    const int base = blockIdx.x * 16;

    #pragma unroll 1
    for (int q = 0; q < 4; ++q) {
        const int node = base + w * 4 + q;
        const bool active = node < N;

        float acc[8] = {};

        int beg = 0, num = 0;
        if (active) { beg = row_start[node]; num = cnt[node]; }
        if (active && s == 0) {   // self-loop once
            const uint4 v = h4[(size_t)node * 16 + li];
            acc[0] += bf16_lo(v.x); acc[1] += bf16_hi(v.x);
            acc[2] += bf16_lo(v.y); acc[3] += bf16_hi(v.y);
            acc[4] += bf16_lo(v.z); acc[5] += bf16_hi(v.z);
            acc[6] += bf16_lo(v.w); acc[7] += bf16_hi(v.w);
        }

        // predicated gather: 16 edges / iteration, no divergent tail
        for (int j = 0; j < num; j += 16) {
            uint4 vv[4];
            float mm[4];
            #pragma unroll
            for (int u = 0; u < 4; ++u) {
                const int jj = j + u * 4 + s;
                mm[u] = (jj < num) ? 1.0f : 0.0f;
                const int idx = (jj < num) ? jj : (num - 1);
                vv[u] = h4[(size_t)srcs[beg + idx] * 16 + li];
            }
            #pragma unroll
            for (int u = 0; u < 4; ++u) {
                const float m = mm[u];
                acc[0] = fmaf(bf16_lo(vv[u].x), m, acc[0]);
                acc[1] = fmaf(bf16_hi(vv[u].x), m, acc[1]);
                acc[2] = fmaf(bf16_lo(vv[u].y), m, acc[2]);
                acc[3] = fmaf(bf16_hi(vv[u].y), m, acc[3]);
                acc[4] = fmaf(bf16_lo(vv[u].z), m, acc[4]);
                acc[5] = fmaf(bf16_hi(vv[u].z), m, acc[5]);
                acc[6] = fmaf(bf16_lo(vv[u].w), m, acc[6]);
                acc[7] = fmaf(bf16_hi(vv[u].w), m, acc[7]);
            }
        }
        #pragma unroll
        for (int t = 0; t < 8; ++t) {
            acc[t] += __shfl_xor(acc[t], 16);
            acc[t] += __shfl_xor(acc[t], 32);
        }
        if (active && s == 0) {
            const float di = dinv[node];
            const float4 bb0 = reinterpret_cast<const float4*>(b1)[li * 2];
            const float4 bb1 = reinterpret_cast<const float4*>(b1)[li * 2 + 1];
            const float r0 = fmaxf(fmaf(di, acc[0], bb0.x), 0.0f);
            const float r1 = fmaxf(fmaf(di, acc[1], bb0.y), 0.0f);
            const float r2 = fmaxf(fmaf(di, acc[2], bb0.z), 0.0f);
            const float r3 = fmaxf(fmaf(di, acc[3], bb0.w), 0.0f);
            const float r4 = fmaxf(fmaf(di, acc[4], bb1.x), 0.0f);
            const float r5 = fmaxf(fmaf(di, acc[5], bb1.y), 0.0f);
            const float r6 = fmaxf(fmaf(di, acc[6], bb1.z), 0.0f);
            const float r7 = fmaxf(fmaf(di, acc[7], bb1.w), 0.0f);
            uint4 o;
            o.x = pack_bf16(r0, r1); o.y = pack_bf16(r2, r3);
            o.z = pack_bf16(r4, r5); o.w = pack_bf16(r6, r7);
            const int row = w * 4 + q;
            const int k = li * 8;
            *reinterpret_cast<uint4*>(&rs[row * 128 + (k ^ ((row & 15) << 3))]) = o;
        }
    }
    __syncthreads();   // uniform: no early returns above

    // full mini-GEMM: C[0..15][w*16 .. w*16+15], K=128  (lane reads A row li)
    f32x4 oacc = {};
    #pragma unroll
    for (int kk = 0; kk < 4; ++kk) {
        const int k0 = kk * 32 + s * 8;
        const bf16x8 af = *reinterpret_cast<const bf16x8*>(&rs[li * 128 + (k0 ^ ((li & 15) << 3))]);
        const int c = w * 16 + li;
        const bf16x8 bfr = *reinterpret_cast<const bf16x8*>(&w2s[c * 128 + (k0 ^ ((c & 15) << 3))]);
        oacc = __builtin_amdgcn_mfma_f32_16x16x32_bf16(af, bfr, oacc, 0, 0, 0);
    }
    // D layout: row = s*4 + reg, col = li within wave's 16-col block
    #pragma unroll
    for (int q = 0; q < 4; ++q) {
        const int nd = base + s * 4 + q;
        if (nd < N) {
            const float dv = dinv[nd];
            h2[(size_t)nd * 64 + w * 16 + li] = __float2bfloat16(oacc[q] * dv);
        }
    }
}

// --- layer-2 agg + bias + log_softmax: 8 slots x 8 lanes x uint4 (full row) -
__global__ __launch_bounds__(256) void agg2_lsm8(const int* __restrict__ row_start,
                                                 const int* __restrict__ cnt,
                                                 const int* __restrict__ srcs,
                                                 const float* __restrict__ dinv,
                                                 const uint4* __restrict__ h2r,  // [N][8] (64 bf16)
                                                 const float* __restrict__ b2,
                                                 float* __restrict__ out, int N) {
    int node = blockIdx.x * 4 + (threadIdx.x >> 6);
    if (node >= N) return;
    const int lane = threadIdx.x & 63;
    const int s = lane >> 3, li = lane & 7;

    float acc[8] = {};
    if (s == 0) {   // self-loop
        const uint4 v = h2r[(size_t)node * 8 + li];
        acc[0] += bf16_lo(v.x); acc[1] += bf16_hi(v.x);
        acc[2] += bf16_lo(v.y); acc[3] += bf16_hi(v.y);
        acc[4] += bf16_lo(v.z); acc[5] += bf16_hi(v.z);
        acc[6] += bf16_lo(v.w); acc[7] += bf16_hi(v.w);
    }
    const int beg = row_start[node];
    const int num = cnt[node];
    for (int j = 0; j < num; j += 16) {
        uint4 vv[2];
        float mm[2];
        #pragma unroll
        for (int u = 0; u < 2; ++u) {
            const int jj = j + u * 8 + s;
            mm[u] = (jj < num) ? 1.0f : 0.0f;
            const int idx = (jj < num) ? jj : (num - 1);
            vv[u] = h2r[(size_t)srcs[beg + idx] * 8 + li];
        }
        #pragma unroll
        for (int u = 0; u < 2; ++u) {
            const float m = mm[u];
            acc[0] = fmaf(bf16_lo(vv[u].x), m, acc[0]);
            acc[1] = fmaf(bf16_hi(vv[u].x), m, acc[1]);
            acc[2] = fmaf(bf16_lo(vv[u].y), m, acc[2]);
            acc[3] = fmaf(bf16_hi(vv[u].y), m, acc[3]);
            acc[4] = fmaf(bf16_lo(vv[u].z), m, acc[4]);
            acc[5] = fmaf(bf16_hi(vv[u].z), m, acc[5]);
            acc[6] = fmaf(bf16_lo(vv[u].w), m, acc[6]);
            acc[7] = fmaf(bf16_hi(vv[u].w), m, acc[7]);
        }
    }
    #pragma unroll
    for (int t = 0; t < 8; ++t) {
        acc[t] += __shfl_xor(acc[t], 8);
        acc[t] += __shfl_xor(acc[t], 16);
        acc[t] += __shfl_xor(acc[t], 32);
    }
    const float di = dinv[node];
    const float4 bb0 = reinterpret_cast<const float4*>(b2)[li * 2];
    const float4 bb1 = reinterpret_cast<const float4*>(b2)[li * 2 + 1];
    float v0 = fmaf(di, acc[0], bb0.x);
    float v1 = fmaf(di, acc[1], bb0.y);
    float v2 = fmaf(di, acc[2], bb0.z);
    float v3 = fmaf(di, acc[3], bb0.w);
    float v4 = fmaf(di, acc[4], bb1.x);
    float v5 = fmaf(di, acc[5], bb1.y);
    float v6 = fmaf(di, acc[6], bb1.z);
    float v7 = fmaf(di, acc[7], bb1.w);
    float m = fmaxf(fmaxf(fmaxf(v0, v1), fmaxf(v2, v3)),
                    fmaxf(fmaxf(v4, v5), fmaxf(v6, v7)));
    #pragma unroll
    for (int o = 4; o > 0; o >>= 1) m = fmaxf(m, __shfl_xor(m, o));
    float es = expf(v0 - m) + expf(v1 - m) + expf(v2 - m) + expf(v3 - m)
             + expf(v4 - m) + expf(v5 - m) + expf(v6 - m) + expf(v7 - m);
    #pragma unroll
    for (int o = 4; o > 0; o >>= 1) es += __shfl_xor(es, o);
    if (s == 0) {
        const float lse = m + logf(es);
        float4 r0, r1;
        r0.x = v0 - lse; r0.y = v1 - lse; r0.z = v2 - lse; r0.w = v3 - lse;
        r1.x = v4 - lse; r1.y = v5 - lse; r1.z = v6 - lse; r1.w = v7 - lse;
        float4* op = reinterpret_cast<float4*>(out) + (size_t)node * 16 + li * 2;
        op[0] = r0;
        op[1] = r1;
    }
}

// ---------------------------------------------------------------------------
extern "C" void kernel_launch(void* const* d_in, const int* in_sizes, int n_in,
                              void* d_out, int out_size, void* d_ws, size_t ws_size,
                              hipStream_t stream) {
    const float* x  = (const float*)d_in[0];
    const int*   ei = (const int*)d_in[1];
    const float* W1 = (const float*)d_in[2];
    const float* b1 = (const float*)d_in[3];
    const float* W2 = (const float*)d_in[4];
    const float* b2 = (const float*)d_in[5];
    float* out = (float*)d_out;

    const int N = in_sizes[0] / 512;   // 100000
    const int E = in_sizes[1] / 2;     // 1600000
    const int* src = ei;
    const int* dst = ei + E;

    const int NBUCKET = (N + 255) >> BSHIFT;      // 391
    const int NB_E    = (E + EB - 1) / EB;        // 391
    const int T       = NBUCKET * NB_E;           // 152881
    const int nbb     = (T + 255) / 256;          // 598

    // workspace layout
    char* ws = (char*)d_ws;
    size_t o = 0;
    auto take = [&](size_t bytes) { char* p = ws + o; o = (o + bytes + 255) & ~(size_t)255; return p; };
    int*            cnt       = (int*)take((size_t)N * 4);
    int*            bsum      = (int*)take(1024 * 4);
    int*            row_start = (int*)take((size_t)N * 4);
    float*          dinv      = (float*)take((size_t)N * 4);
    int*            srcs      = (int*)take((size_t)E * 4);
    unsigned*       ebuf      = (unsigned*)take((size_t)E * 4);
    int*            counts    = (int*)take((size_t)T * 4);
    int*            offs      = (int*)take((size_t)T * 4);
    __hip_bfloat16* W1t       = (__hip_bfloat16*)take((size_t)128 * 512 * 2);
    __hip_bfloat16* W2t       = (__hip_bfloat16*)take((size_t)64 * 128 * 2);
    __hip_bfloat16* h         = (__hip_bfloat16*)take((size_t)N * 128 * 2);   // h' = dinv*h
    __hip_bfloat16* h2        = (__hip_bfloat16*)take((size_t)N * 64 * 2);    // h2' = dinv*h2

    const int mb = (N + 63) / 64;      // 1563 blocks (64-row tiles)

    // ---- CSR build (bucketed counting sort) + weight convert ----
    hist_conv<<<NB_E + 288, 256, 0, stream>>>(dst, counts, W1, W2, W1t, W2t,
                                              NB_E, NBUCKET, E);
    scan_block_sums<<<nbb, 256, 0, stream>>>(counts, bsum, T);
    scan_offs<<<nbb, 256, 0, stream>>>(counts, bsum, offs, T);
    scatter_bucketed<<<NB_E, 256, 0, stream>>>(src, dst, offs, ebuf, NB_E, NBUCKET, E);
    bucket_csr<<<NBUCKET, 256, 0, stream>>>(ebuf, offs, row_start, cnt, dinv, srcs,
                                            NB_E, NBUCKET, N, E);

    // layer 1 + fused layer-2 transform
    gemm1_mfma<<<mb, 256, 0, stream>>>(x, W1t, dinv, h, N);
    agg1_fused<<<(N + 15) / 16, 256, 0, stream>>>(row_start, cnt, srcs, dinv,
                                                  (const uint4*)h, b1, W2t, h2, N);

    // layer-2 aggregation + log_softmax
    agg2_lsm8<<<(N + 3) / 4, 256, 0, stream>>>(row_start, cnt, srcs, dinv,
                                               (const uint4*)h2, b2, out, N);
}